// Round 1
// baseline (44043.039 us; speedup 1.0000x reference)
//
#include <hip/hip_runtime.h>
#include <hip/hip_bf16.h>
#include <cstddef>

#define BB 1024
#define TT 64
#define CC 66
#define HH 1024
#define SS 12
#define LL 12
#define XROW (TT*CC)   // 4224 floats per batch row of x

// ---------------------------------------------------------------------------
// GRU kernel: h_out = GRU(h_in, x_row)
// grid (HH/32=32, BB/64=16), block 256. Tile: 64 b-rows x 32 j-cols.
// Computes all three gate dot products (vs Wi over K=66 and Wh over K=1024)
// and applies the gate nonlinearity in one kernel.
// ---------------------------------------------------------------------------
struct GruSmem {
  float As[64][33];      // staged input vectors [b][k]
  float Ws[3][32][33];   // staged weight rows  [gate][j][k]
};

__device__ __forceinline__ void gru_phase(
    const float* __restrict__ V, size_t vs,
    const float* __restrict__ W, int wld, int K,
    int b0, int j0, int tid, int tb4, int tj2,
    float (&ar)[4][2], float (&az)[4][2], float (&aN)[4][2],
    GruSmem& sm)
{
  for (int k0 = 0; k0 < K; k0 += 32) {
    int kt = K - k0; if (kt > 32) kt = 32;
    __syncthreads();   // protect LDS reuse from previous chunk's compute
    for (int idx = tid; idx < 64*32; idx += 256) {
      int r = idx >> 5, c = idx & 31;
      sm.As[r][c] = (c < kt) ? V[(size_t)(b0 + r) * vs + k0 + c] : 0.f;
    }
    #pragma unroll
    for (int g = 0; g < 3; ++g)
      for (int idx = tid; idx < 32*32; idx += 256) {
        int r = idx >> 5, c = idx & 31;
        sm.Ws[g][r][c] = (c < kt) ? W[(size_t)(g*HH + j0 + r) * wld + k0 + c] : 0.f;
      }
    __syncthreads();
    #pragma unroll 8
    for (int kk = 0; kk < 32; ++kk) {
      float a0 = sm.As[tb4+0][kk], a1 = sm.As[tb4+1][kk],
            a2 = sm.As[tb4+2][kk], a3 = sm.As[tb4+3][kk];
      #pragma unroll
      for (int jj = 0; jj < 2; ++jj) {
        float wr = sm.Ws[0][tj2+jj][kk];
        float wz = sm.Ws[1][tj2+jj][kk];
        float wn = sm.Ws[2][tj2+jj][kk];
        ar[0][jj] = fmaf(a0, wr, ar[0][jj]);
        ar[1][jj] = fmaf(a1, wr, ar[1][jj]);
        ar[2][jj] = fmaf(a2, wr, ar[2][jj]);
        ar[3][jj] = fmaf(a3, wr, ar[3][jj]);
        az[0][jj] = fmaf(a0, wz, az[0][jj]);
        az[1][jj] = fmaf(a1, wz, az[1][jj]);
        az[2][jj] = fmaf(a2, wz, az[2][jj]);
        az[3][jj] = fmaf(a3, wz, az[3][jj]);
        aN[0][jj] = fmaf(a0, wn, aN[0][jj]);
        aN[1][jj] = fmaf(a1, wn, aN[1][jj]);
        aN[2][jj] = fmaf(a2, wn, aN[2][jj]);
        aN[3][jj] = fmaf(a3, wn, aN[3][jj]);
      }
    }
  }
}

__global__ __launch_bounds__(256) void gru_kernel(
    const float* __restrict__ h_in,
    const float* __restrict__ xv, int xstride,
    const float* __restrict__ Wi, const float* __restrict__ Wh,
    const float* __restrict__ bi, const float* __restrict__ bh,
    float* __restrict__ h_out)
{
  __shared__ GruSmem sm;
  int tid = threadIdx.x;
  int tj2 = (tid & 15) * 2;
  int tb4 = (tid >> 4) * 4;
  int j0 = blockIdx.x * 32, b0 = blockIdx.y * 64;
  float ar[4][2] = {}; float az[4][2] = {}; float an[4][2] = {}; float ah[4][2] = {};
  // input contribution (K = 66)
  gru_phase(xv, (size_t)xstride, Wi, CC, CC, b0, j0, tid, tb4, tj2, ar, az, an, sm);
  // hidden contribution (K = 1024); n-gate hidden part kept separate (ah)
  gru_phase(h_in, HH, Wh, HH, HH, b0, j0, tid, tb4, tj2, ar, az, ah, sm);
  #pragma unroll
  for (int i = 0; i < 4; ++i) {
    int b = b0 + tb4 + i;
    #pragma unroll
    for (int jj = 0; jj < 2; ++jj) {
      int j = j0 + tj2 + jj;
      float rv = ar[i][jj] + bi[j] + bh[j];
      float zv = az[i][jj] + bi[HH + j] + bh[HH + j];
      float r = 1.f / (1.f + __expf(-rv));
      float z = 1.f / (1.f + __expf(-zv));
      float n = tanhf(an[i][jj] + bi[2*HH + j] + r * (ah[i][jj] + bh[2*HH + j]));
      float hp = h_in[(size_t)b * HH + j];
      h_out[(size_t)b * HH + j] = (1.f - z) * n + z * hp;
    }
  }
}

// ---------------------------------------------------------------------------
// wst row kernel: dst[b*10*H + h] = enc_b[h] + src_row(b) . encWT[:,h]
// grid (HH/256=4, BB), block 256. encWT is (CC,HH) transposed enc_W.
// ---------------------------------------------------------------------------
__global__ __launch_bounds__(256) void wst_row_kernel(
    const float* __restrict__ src, int src_stride,
    const float* __restrict__ encWT, const float* __restrict__ encb,
    float* __restrict__ dst)
{
  __shared__ float s[CC];
  int b = blockIdx.y;
  int h = blockIdx.x * 256 + threadIdx.x;
  if (threadIdx.x < CC) s[threadIdx.x] = src[(size_t)b * src_stride + threadIdx.x];
  __syncthreads();
  float acc = encb[h];
  #pragma unroll
  for (int k = 0; k < CC; ++k) acc = fmaf(s[k], encWT[(size_t)k * HH + h], acc);
  dst[(size_t)b * (10 * HH) + h] = acc;
}

__global__ __launch_bounds__(256) void transpose_encW(
    const float* __restrict__ W, float* __restrict__ WT)
{
  int k = blockIdx.x;
  int h = blockIdx.y * 256 + threadIdx.x;
  WT[(size_t)k * HH + h] = W[(size_t)h * CC + k];
}

__global__ __launch_bounds__(256) void copy_last_kernel(
    const float* __restrict__ x, float* __restrict__ last)
{
  int idx = blockIdx.x * 256 + threadIdx.x;
  if (idx < BB * CC) {
    int b = idx / CC, c = idx - b * CC;
    last[idx] = x[(size_t)b * XROW + 63 * CC + c];
  }
}

// ---------------------------------------------------------------------------
// MLP-mini kernel: one block per batch element. f (H x S) kept in registers
// (each thread owns 4 rows). 12 layers of SxS matmul + LayerNorm over H +
// residual, then folded out_W+merge_W epilogue. Writes out[:,t,:], updates last.
// ---------------------------------------------------------------------------
__global__ __launch_bounds__(256) void mlp_kernel(
    const float* __restrict__ whp, const float* __restrict__ hdec,
    const float* __restrict__ wst, int ring0,
    const float* __restrict__ seqW, const float* __restrict__ seqb,
    const float* __restrict__ lnA, const float* __restrict__ lnB,
    const float* __restrict__ outW, const float* __restrict__ outb,
    const float* __restrict__ mrgW, const float* __restrict__ mrgb,
    float* __restrict__ last, float* __restrict__ outp)
{
  int b = blockIdx.x, tid = threadIdx.x;
  int lane = tid & 63, wid = tid >> 6;
  __shared__ float sw[LL][SS][SS];
  __shared__ float sb[LL][SS];
  __shared__ float red[4][24];
  __shared__ float mustd[24];
  __shared__ float g_lds[HH];
  __shared__ float nc[CC];
  for (int idx = tid; idx < LL*SS*SS; idx += 256) (&sw[0][0][0])[idx] = seqW[idx];
  for (int idx = tid; idx < LL*SS; idx += 256) (&sb[0][0])[idx] = seqb[idx];

  float fr[4][SS];
  {
    const float* whb = whp + (size_t)b * HH;
    const float* hb  = hdec + (size_t)b * HH;
    #pragma unroll
    for (int r = 0; r < 4; ++r) {
      int h = tid + r * 256;
      fr[r][0]  = whb[h];
      fr[r][11] = hb[h];
      #pragma unroll
      for (int w = 0; w < 10; ++w) {
        int slot = ring0 + w; if (slot >= 10) slot -= 10;
        fr[r][1 + w] = wst[((size_t)b * 10 + slot) * HH + h];
      }
    }
  }
  __syncthreads();

  float y[4][SS];
  for (int l = 0; l < LL; ++l) {
    float ps[SS], pq[SS];
    #pragma unroll
    for (int s = 0; s < SS; ++s) {
      float bv = sb[l][s];
      float a0 = bv, a1 = bv, a2 = bv, a3 = bv;
      #pragma unroll
      for (int k = 0; k < SS; ++k) {
        float wv = sw[l][s][k];
        a0 = fmaf(fr[0][k], wv, a0);
        a1 = fmaf(fr[1][k], wv, a1);
        a2 = fmaf(fr[2][k], wv, a2);
        a3 = fmaf(fr[3][k], wv, a3);
      }
      y[0][s] = a0; y[1][s] = a1; y[2][s] = a2; y[3][s] = a3;
      ps[s] = a0 + a1 + a2 + a3;
      pq[s] = a0*a0 + a1*a1 + a2*a2 + a3*a3;
    }
    #pragma unroll
    for (int s = 0; s < SS; ++s) {
      #pragma unroll
      for (int o = 32; o > 0; o >>= 1) {
        ps[s] += __shfl_xor(ps[s], o);
        pq[s] += __shfl_xor(pq[s], o);
      }
    }
    if (lane == 0) {
      #pragma unroll
      for (int s = 0; s < SS; ++s) { red[wid][s] = ps[s]; red[wid][12 + s] = pq[s]; }
    }
    __syncthreads();
    if (tid < 12) {
      float S = red[0][tid] + red[1][tid] + red[2][tid] + red[3][tid];
      float Q = red[0][12+tid] + red[1][12+tid] + red[2][12+tid] + red[3][12+tid];
      float mu = S * (1.f / HH);
      float var = Q * (1.f / HH) - mu * mu;
      mustd[tid] = mu;
      mustd[12 + tid] = 1.f / sqrtf(var + 1e-5f);
    }
    __syncthreads();
    #pragma unroll
    for (int r = 0; r < 4; ++r) {
      int h = tid + r * 256;
      float al = lnA[(size_t)l * HH + h];
      float be = lnB[(size_t)l * HH + h];
      #pragma unroll
      for (int s = 0; s < SS; ++s)
        fr[r][s] += (y[r][s] - mustd[s]) * mustd[12 + s] * al + be;
    }
    // next layer's first barrier (after red write) keeps red/mustd hazard-free
  }

  // epilogue: new[c] = sum_h (sum_s mW[s] f[h][s]) * outW[c][h]
  //                    + outb[c]*sum(mW) + mb + last[b][c]
  float mwv[SS];
  #pragma unroll
  for (int s = 0; s < SS; ++s) mwv[s] = mrgW[s];
  float smw = 0.f;
  #pragma unroll
  for (int s = 0; s < SS; ++s) smw += mwv[s];
  float mbv = mrgb[0];
  #pragma unroll
  for (int r = 0; r < 4; ++r) {
    float g = 0.f;
    #pragma unroll
    for (int s = 0; s < SS; ++s) g = fmaf(mwv[s], fr[r][s], g);
    g_lds[tid + r * 256] = g;
  }
  __syncthreads();
  for (int i = 0; i < 17; ++i) {
    int c = wid + 4 * i;
    if (c < CC) {
      const float* ow = outW + (size_t)c * HH;
      float acc = 0.f;
      #pragma unroll
      for (int q = 0; q < 16; ++q) acc = fmaf(g_lds[lane + q*64], ow[lane + q*64], acc);
      #pragma unroll
      for (int o = 32; o > 0; o >>= 1) acc += __shfl_xor(acc, o);
      if (lane == 0) nc[c] = acc + outb[c] * smw + mbv + last[(size_t)b * CC + c];
    }
  }
  __syncthreads();
  if (tid < CC) {
    float nv = nc[tid];
    outp[(size_t)b * XROW + tid] = nv;   // out[b][t][c]; outp = d_out + t*CC
    last[(size_t)b * CC + tid] = nv;
  }
}

// ---------------------------------------------------------------------------
extern "C" void kernel_launch(void* const* d_in, const int* in_sizes, int n_in,
                              void* d_out, int out_size, void* d_ws, size_t ws_size,
                              hipStream_t stream) {
  const float* x    = (const float*)d_in[0];
  const float* gWi  = (const float*)d_in[1];
  const float* gWh  = (const float*)d_in[2];
  const float* gbi  = (const float*)d_in[3];
  const float* gbh  = (const float*)d_in[4];
  const float* encW = (const float*)d_in[5];
  const float* encb = (const float*)d_in[6];
  const float* seqW = (const float*)d_in[7];
  const float* seqb = (const float*)d_in[8];
  const float* lnA  = (const float*)d_in[9];
  const float* lnB  = (const float*)d_in[10];
  const float* outW = (const float*)d_in[11];
  const float* outb = (const float*)d_in[12];
  const float* mrgW = (const float*)d_in[13];
  const float* mrgb = (const float*)d_in[14];
  float* out = (float*)d_out;

  float* ws   = (float*)d_ws;
  float* hA   = ws;                       // 1048576
  float* hB   = hA + (1u << 20);          // 1048576
  float* whp  = hB + (1u << 20);          // 1048576 (window_history)
  float* wst  = whp + (1u << 20);         // 1024*10*1024 = 10485760 (ring)
  float* last = wst + 10485760u;          // 1024*66
  float* encWT = last + (size_t)BB * CC;  // 66*1024
  size_t need = (size_t)(3u << 20) + 10485760u + 2u * (size_t)BB * CC;
  if (ws_size < need * sizeof(float)) return;  // workspace too small -> fail loudly

  hipMemsetAsync(hA, 0, (size_t)(1u << 20) * sizeof(float), stream);
  transpose_encW<<<dim3(CC, HH/256), 256, 0, stream>>>(encW, encWT);
  copy_last_kernel<<<dim3((BB*CC + 255)/256), 256, 0, stream>>>(x, last);

  const dim3 ggrid(HH/32, BB/64);  // (32,16) = 512 blocks

  // ---- encoder: 63 GRU steps over x[:, 0..62, :] ----
  float* hin = hA; float* hout = hB;
  for (int t = 0; t < 63; ++t) {
    gru_kernel<<<ggrid, 256, 0, stream>>>(hin, x + (size_t)t * CC, XROW,
                                          gWi, gWh, gbi, gbh, hout);
    float* tmp = hin; hin = hout; hout = tmp;
  }
  // hin == h_enc. window_history = GRU(h_enc, x[:,63,:]) (== decode-step-0 h)
  gru_kernel<<<ggrid, 256, 0, stream>>>(hin, x + (size_t)63 * CC, XROW,
                                        gWi, gWh, gbi, gbh, whp);

  // ---- initial wst ring: rows of buf0 = x[:, 54..63, :] ----
  for (int w = 0; w < 10; ++w)
    wst_row_kernel<<<dim3(HH/256, BB), 256, 0, stream>>>(
        x + (size_t)(54 + w) * CC, XROW, encWT, encb, wst + (size_t)w * HH);

  // ---- decoder: 64 steps ----
  float* bufs[2] = {hA, hB};   // both free now (h_enc dead after whp)
  float* hc = whp;             // h for t=0 equals window_history
  for (int t = 0; t < 64; ++t) {
    if (t > 0) {
      float* hn = bufs[t & 1];
      gru_kernel<<<ggrid, 256, 0, stream>>>(hc, last, CC, gWi, gWh, gbi, gbh, hn);
      hc = hn;
      // wst row for the frame produced at step t-1 (currently in `last`)
      wst_row_kernel<<<dim3(HH/256, BB), 256, 0, stream>>>(
          last, CC, encWT, encb, wst + (size_t)((t + 9) % 10) * HH);
    }
    mlp_kernel<<<dim3(BB), 256, 0, stream>>>(
        whp, hc, wst, t % 10, seqW, seqb, lnA, lnB, outW, outb, mrgW, mrgb,
        last, out + (size_t)t * CC);
  }
}

// Round 2
// 14934.866 us; speedup vs baseline: 2.9490x; 2.9490x over previous
//
#include <hip/hip_runtime.h>
#include <hip/hip_bf16.h>
#include <cstddef>
#include <cstdint>

#define BB 1024
#define TT 64
#define CC 66
#define HH 1024
#define SS 12
#define LL 12
#define XROW (TT*CC)   // 4224 floats per batch row of x

typedef __attribute__((ext_vector_type(8))) __bf16 bfrag;
typedef __attribute__((ext_vector_type(4))) float f32x4;
typedef __attribute__((ext_vector_type(8))) short s8v;

__device__ __forceinline__ unsigned short f2bf(float f) {
  unsigned int u = __builtin_bit_cast(unsigned int, f);
  unsigned int r = u + 0x7FFFu + ((u >> 16) & 1u);
  return (unsigned short)(r >> 16);
}
__device__ __forceinline__ float bf2f(unsigned short h) {
  unsigned int u = ((unsigned int)h) << 16;
  return __builtin_bit_cast(float, u);
}

__device__ __forceinline__ void gload16(const void* g, void* l) {
  __builtin_amdgcn_global_load_lds(
      (const __attribute__((address_space(1))) unsigned int*)g,
      (__attribute__((address_space(3))) unsigned int*)l, 16, 0, 0);
}

// ---------------------------------------------------------------------------
// Split-bf16 MFMA GRU step.
// Wgc layout: [jb(32)][kc(35)][r(128)][32] bf16 (hi & lo tensors), where
// r = g*32+jj encodes gate-group g in {r,z,n_h,n_x}, with 16B-unit swizzle
// cb ^= (r&3) baked in. A-side (h hi/lo, x-tail hi/lo) has the same bake.
// Block: 64 M-rows x 32 j's (=128 gathered N-cols). 256 thr, 4 waves (2Mx2N).
// ---------------------------------------------------------------------------
__global__ __launch_bounds__(256) void gru_mfma(
    const unsigned short* __restrict__ Ahi, const unsigned short* __restrict__ Alo,
    const float* __restrict__ hprev,
    const unsigned short* __restrict__ Xhi, const unsigned short* __restrict__ Xlo,
    const unsigned short* __restrict__ Whi, const unsigned short* __restrict__ Wlo,
    const float* __restrict__ bi, const float* __restrict__ bh,
    float* __restrict__ hout_f32,
    unsigned short* __restrict__ hout_hi, unsigned short* __restrict__ hout_lo)
{
  __shared__ __align__(16) unsigned short AsH[64*32];
  __shared__ __align__(16) unsigned short AsL[64*32];
  __shared__ __align__(16) unsigned short BsH[128*32];
  __shared__ __align__(16) unsigned short BsL[128*32];
  __shared__ float gacc[64*132];

  const int tid = threadIdx.x, lane = tid & 63, wid = tid >> 6;
  const int b0 = blockIdx.x * 64, jb = blockIdx.y;
  const int wm = wid >> 1, wn = wid & 1;

  f32x4 acc[2][4] = {};

  const int aR = lane >> 2, aC = lane & 3;  // 16 rows/wave-instr, 4x16B units/row

  for (int kc = 0; kc < 35; ++kc) {
    __syncthreads();
    // ---- stage A (hi+lo): 64x32 bf16 each; wave w stages rows 16w..16w+15
    {
      const unsigned short *shi, *slo; size_t go;
      int row = wid * 16 + aR;
      if (kc < 32) {
        go = (size_t)(b0 + row) * 1024 + (size_t)kc * 32 + aC * 8;
        shi = Ahi; slo = Alo;
      } else {
        go = (size_t)(b0 + row) * 96 + (size_t)(kc - 32) * 32 + aC * 8;
        shi = Xhi; slo = Xlo;
      }
      gload16(shi + go, AsH + wid * 512);
      gload16(slo + go, AsL + wid * 512);
    }
    // ---- stage B (hi+lo): 128x32 bf16 each; wave w stages rows 32w..32w+31
    {
      size_t base = ((size_t)jb * 35 + kc) * 128 * 32;
      size_t go0 = base + (size_t)(wid * 32 + aR) * 32 + aC * 8;
      size_t go1 = base + (size_t)(wid * 32 + 16 + aR) * 32 + aC * 8;
      gload16(Whi + go0, BsH + wid * 1024);
      gload16(Whi + go1, BsH + wid * 1024 + 512);
      gload16(Wlo + go0, BsL + wid * 1024);
      gload16(Wlo + go1, BsL + wid * 1024 + 512);
    }
    __syncthreads();   // drains vmcnt(0) before LDS consume

    bfrag ah[2], al[2], bhf[4], blf[4];
    #pragma unroll
    for (int mh = 0; mh < 2; ++mh) {
      int r = wm * 32 + mh * 16 + (lane & 15);
      int cb = (lane >> 4) ^ (r & 3);
      int off = r * 32 + cb * 8;
      ah[mh] = __builtin_bit_cast(bfrag, *(const s8v*)(AsH + off));
      al[mh] = __builtin_bit_cast(bfrag, *(const s8v*)(AsL + off));
    }
    #pragma unroll
    for (int nf = 0; nf < 4; ++nf) {
      int r = wn * 64 + nf * 16 + (lane & 15);
      int cb = (lane >> 4) ^ (r & 3);
      int off = r * 32 + cb * 8;
      bhf[nf] = __builtin_bit_cast(bfrag, *(const s8v*)(BsH + off));
      blf[nf] = __builtin_bit_cast(bfrag, *(const s8v*)(BsL + off));
    }
    #pragma unroll
    for (int mh = 0; mh < 2; ++mh)
      #pragma unroll
      for (int nf = 0; nf < 4; ++nf) {
        acc[mh][nf] = __builtin_amdgcn_mfma_f32_16x16x32_bf16(ah[mh], bhf[nf], acc[mh][nf], 0, 0, 0);
        acc[mh][nf] = __builtin_amdgcn_mfma_f32_16x16x32_bf16(ah[mh], blf[nf], acc[mh][nf], 0, 0, 0);
        acc[mh][nf] = __builtin_amdgcn_mfma_f32_16x16x32_bf16(al[mh], bhf[nf], acc[mh][nf], 0, 0, 0);
      }
  }

  // C/D layout: col = lane&15, row = (lane>>4)*4 + reg  [m89-verified]
  #pragma unroll
  for (int mh = 0; mh < 2; ++mh)
    #pragma unroll
    for (int nf = 0; nf < 4; ++nf)
      #pragma unroll
      for (int q = 0; q < 4; ++q) {
        int m = wm * 32 + mh * 16 + (lane >> 4) * 4 + q;
        int n = wn * 64 + nf * 16 + (lane & 15);
        gacc[m * 132 + n] = acc[mh][nf][q];
      }
  __syncthreads();

  // gates epilogue: groups at n = jj, 32+jj, 64+jj, 96+jj
  #pragma unroll
  for (int i = 0; i < 8; ++i) {
    int idx = tid + i * 256;
    int m = idx >> 5, jj = idx & 31;
    int b = b0 + m, j = jb * 32 + jj;
    float rr = gacc[m * 132 + jj]      + bi[j] + bh[j];
    float zz = gacc[m * 132 + 32 + jj] + bi[HH + j] + bh[HH + j];
    float nh = gacc[m * 132 + 64 + jj] + bh[2 * HH + j];
    float nx = gacc[m * 132 + 96 + jj] + bi[2 * HH + j];
    float r = 1.f / (1.f + __expf(-rr));
    float z = 1.f / (1.f + __expf(-zz));
    float n = tanhf(nx + r * nh);
    float hp = hprev[(size_t)b * HH + j];
    float hv = (1.f - z) * n + z * hp;
    hout_f32[(size_t)b * HH + j] = hv;
    unsigned short hi = f2bf(hv);
    float lo = hv - bf2f(hi);
    int cb = ((jj >> 3) & 3) ^ (b & 3);
    size_t dst = (size_t)b * 1024 + (size_t)(j & ~31) + cb * 8 + (j & 7);
    hout_hi[dst] = hi;
    hout_lo[dst] = f2bf(lo);
  }
}

// ---------------------------------------------------------------------------
// Prep: build Wgc hi/lo (gathered 4-group, chunked, swizzle-baked)
// ---------------------------------------------------------------------------
__global__ __launch_bounds__(256) void prep_wgc(
    const float* __restrict__ Wh, const float* __restrict__ Wi,
    unsigned short* __restrict__ Whi, unsigned short* __restrict__ Wlo)
{
  size_t idx = (size_t)blockIdx.x * 256 + threadIdx.x;
  if (idx >= (size_t)4096 * 1120) return;
  int k = (int)(idx % 1120);
  int rg = (int)(idx / 1120);
  int jbv = rg >> 7, r = rg & 127, g = r >> 5, jj = r & 31;
  int j = jbv * 32 + jj;
  float v = 0.f;
  if (g == 0)      v = (k < 1024) ? Wh[(size_t)j * HH + k]            : ((k < 1090) ? Wi[(size_t)j * CC + (k - 1024)] : 0.f);
  else if (g == 1) v = (k < 1024) ? Wh[(size_t)(HH + j) * HH + k]     : ((k < 1090) ? Wi[(size_t)(HH + j) * CC + (k - 1024)] : 0.f);
  else if (g == 2) v = (k < 1024) ? Wh[(size_t)(2 * HH + j) * HH + k] : 0.f;
  else             v = (k >= 1024 && k < 1090) ? Wi[(size_t)(2 * HH + j) * CC + (k - 1024)] : 0.f;
  unsigned short hi = f2bf(v);
  float lo = v - bf2f(hi);
  int kc = k >> 5, kk = k & 31;
  int cb = ((kk >> 3) ^ (r & 3)) & 3;
  size_t dst = (((size_t)jbv * 35 + kc) * 128 + r) * 32 + cb * 8 + (kk & 7);
  Whi[dst] = hi;
  Wlo[dst] = f2bf(lo);
}

// Prep: x tails for all 64 steps, padded 66->96, hi/lo, swizzle-baked
__global__ __launch_bounds__(256) void prep_xall(
    const float* __restrict__ x,
    unsigned short* __restrict__ Xhi, unsigned short* __restrict__ Xlo)
{
  size_t idx = (size_t)blockIdx.x * 256 + threadIdx.x;
  if (idx >= (size_t)TT * BB * 96) return;
  int kx = (int)(idx % 96);
  size_t rem = idx / 96;
  int b = (int)(rem % BB);
  int t = (int)(rem / BB);
  float v = (kx < CC) ? x[(size_t)b * XROW + (size_t)t * CC + kx] : 0.f;
  unsigned short hi = f2bf(v);
  float lo = v - bf2f(hi);
  int cb = (((kx >> 3) & 3) ^ (b & 3)) & 3;
  size_t dst = ((size_t)t * BB + b) * 96 + (size_t)(kx & ~31) + cb * 8 + (kx & 7);
  Xhi[dst] = hi;
  Xlo[dst] = f2bf(lo);
}

// ---------------------------------------------------------------------------
// wst row kernel: dst[b*10*H + h] = enc_b[h] + src_row(b) . encWT[:,h]
// ---------------------------------------------------------------------------
__global__ __launch_bounds__(256) void wst_row_kernel(
    const float* __restrict__ src, int src_stride,
    const float* __restrict__ encWT, const float* __restrict__ encb,
    float* __restrict__ dst)
{
  __shared__ float s[CC];
  int b = blockIdx.y;
  int h = blockIdx.x * 256 + threadIdx.x;
  if (threadIdx.x < CC) s[threadIdx.x] = src[(size_t)b * src_stride + threadIdx.x];
  __syncthreads();
  float acc = encb[h];
  #pragma unroll
  for (int k = 0; k < CC; ++k) acc = fmaf(s[k], encWT[(size_t)k * HH + h], acc);
  dst[(size_t)b * (10 * HH) + h] = acc;
}

__global__ __launch_bounds__(256) void transpose_encW(
    const float* __restrict__ W, float* __restrict__ WT)
{
  int k = blockIdx.x;
  int h = blockIdx.y * 256 + threadIdx.x;
  WT[(size_t)k * HH + h] = W[(size_t)h * CC + k];
}

__global__ __launch_bounds__(256) void copy_last_kernel(
    const float* __restrict__ x, float* __restrict__ last)
{
  int idx = blockIdx.x * 256 + threadIdx.x;
  if (idx < BB * CC) {
    int b = idx / CC, c = idx - b * CC;
    last[idx] = x[(size_t)b * XROW + 63 * CC + c];
  }
}

// ---------------------------------------------------------------------------
// MLP-mini kernel (unchanged math) + writes lastpad hi/lo for the next GRU.
// ---------------------------------------------------------------------------
__global__ __launch_bounds__(256) void mlp_kernel(
    const float* __restrict__ whp, const float* __restrict__ hdec,
    const float* __restrict__ wst, int ring0,
    const float* __restrict__ seqW, const float* __restrict__ seqb,
    const float* __restrict__ lnA, const float* __restrict__ lnB,
    const float* __restrict__ outW, const float* __restrict__ outb,
    const float* __restrict__ mrgW, const float* __restrict__ mrgb,
    float* __restrict__ last, float* __restrict__ outp,
    unsigned short* __restrict__ lpH, unsigned short* __restrict__ lpL)
{
  int b = blockIdx.x, tid = threadIdx.x;
  int lane = tid & 63, wid = tid >> 6;
  __shared__ float sw[LL][SS][SS];
  __shared__ float sb[LL][SS];
  __shared__ float red[4][24];
  __shared__ float mustd[24];
  __shared__ float g_lds[HH];
  __shared__ float nc[CC];
  for (int idx = tid; idx < LL*SS*SS; idx += 256) (&sw[0][0][0])[idx] = seqW[idx];
  for (int idx = tid; idx < LL*SS; idx += 256) (&sb[0][0])[idx] = seqb[idx];

  float fr[4][SS];
  {
    const float* whb = whp + (size_t)b * HH;
    const float* hb  = hdec + (size_t)b * HH;
    #pragma unroll
    for (int r = 0; r < 4; ++r) {
      int h = tid + r * 256;
      fr[r][0]  = whb[h];
      fr[r][11] = hb[h];
      #pragma unroll
      for (int w = 0; w < 10; ++w) {
        int slot = ring0 + w; if (slot >= 10) slot -= 10;
        fr[r][1 + w] = wst[((size_t)b * 10 + slot) * HH + h];
      }
    }
  }
  __syncthreads();

  float y[4][SS];
  for (int l = 0; l < LL; ++l) {
    float ps[SS], pq[SS];
    #pragma unroll
    for (int s = 0; s < SS; ++s) {
      float bv = sb[l][s];
      float a0 = bv, a1 = bv, a2 = bv, a3 = bv;
      #pragma unroll
      for (int k = 0; k < SS; ++k) {
        float wv = sw[l][s][k];
        a0 = fmaf(fr[0][k], wv, a0);
        a1 = fmaf(fr[1][k], wv, a1);
        a2 = fmaf(fr[2][k], wv, a2);
        a3 = fmaf(fr[3][k], wv, a3);
      }
      y[0][s] = a0; y[1][s] = a1; y[2][s] = a2; y[3][s] = a3;
      ps[s] = a0 + a1 + a2 + a3;
      pq[s] = a0*a0 + a1*a1 + a2*a2 + a3*a3;
    }
    #pragma unroll
    for (int s = 0; s < SS; ++s) {
      #pragma unroll
      for (int o = 32; o > 0; o >>= 1) {
        ps[s] += __shfl_xor(ps[s], o);
        pq[s] += __shfl_xor(pq[s], o);
      }
    }
    if (lane == 0) {
      #pragma unroll
      for (int s = 0; s < SS; ++s) { red[wid][s] = ps[s]; red[wid][12 + s] = pq[s]; }
    }
    __syncthreads();
    if (tid < 12) {
      float S = red[0][tid] + red[1][tid] + red[2][tid] + red[3][tid];
      float Q = red[0][12+tid] + red[1][12+tid] + red[2][12+tid] + red[3][12+tid];
      float mu = S * (1.f / HH);
      float var = Q * (1.f / HH) - mu * mu;
      mustd[tid] = mu;
      mustd[12 + tid] = 1.f / sqrtf(var + 1e-5f);
    }
    __syncthreads();
    #pragma unroll
    for (int r = 0; r < 4; ++r) {
      int h = tid + r * 256;
      float al = lnA[(size_t)l * HH + h];
      float be = lnB[(size_t)l * HH + h];
      #pragma unroll
      for (int s = 0; s < SS; ++s)
        fr[r][s] += (y[r][s] - mustd[s]) * mustd[12 + s] * al + be;
    }
  }

  float mwv[SS];
  #pragma unroll
  for (int s = 0; s < SS; ++s) mwv[s] = mrgW[s];
  float smw = 0.f;
  #pragma unroll
  for (int s = 0; s < SS; ++s) smw += mwv[s];
  float mbv = mrgb[0];
  #pragma unroll
  for (int r = 0; r < 4; ++r) {
    float g = 0.f;
    #pragma unroll
    for (int s = 0; s < SS; ++s) g = fmaf(mwv[s], fr[r][s], g);
    g_lds[tid + r * 256] = g;
  }
  __syncthreads();
  for (int i = 0; i < 17; ++i) {
    int c = wid + 4 * i;
    if (c < CC) {
      const float* ow = outW + (size_t)c * HH;
      float acc = 0.f;
      #pragma unroll
      for (int q = 0; q < 16; ++q) acc = fmaf(g_lds[lane + q*64], ow[lane + q*64], acc);
      #pragma unroll
      for (int o = 32; o > 0; o >>= 1) acc += __shfl_xor(acc, o);
      if (lane == 0) nc[c] = acc + outb[c] * smw + mbv + last[(size_t)b * CC + c];
    }
  }
  __syncthreads();
  if (tid < CC) {
    float nv = nc[tid];
    outp[(size_t)b * XROW + tid] = nv;
    last[(size_t)b * CC + tid] = nv;
    unsigned short hi = f2bf(nv);
    float lo = nv - bf2f(hi);
    int cb = (((tid >> 3) & 3) ^ (b & 3)) & 3;
    size_t dst = (size_t)b * 96 + (size_t)(tid & ~31) + cb * 8 + (tid & 7);
    lpH[dst] = hi;
    lpL[dst] = f2bf(lo);
  }
}

// ---------------------------------------------------------------------------
extern "C" void kernel_launch(void* const* d_in, const int* in_sizes, int n_in,
                              void* d_out, int out_size, void* d_ws, size_t ws_size,
                              hipStream_t stream) {
  const float* x    = (const float*)d_in[0];
  const float* gWi  = (const float*)d_in[1];
  const float* gWh  = (const float*)d_in[2];
  const float* gbi  = (const float*)d_in[3];
  const float* gbh  = (const float*)d_in[4];
  const float* encW = (const float*)d_in[5];
  const float* encb = (const float*)d_in[6];
  const float* seqW = (const float*)d_in[7];
  const float* seqb = (const float*)d_in[8];
  const float* lnA  = (const float*)d_in[9];
  const float* lnB  = (const float*)d_in[10];
  const float* outW = (const float*)d_in[11];
  const float* outb = (const float*)d_in[12];
  const float* mrgW = (const float*)d_in[13];
  const float* mrgb = (const float*)d_in[14];
  float* out = (float*)d_out;

  char* p = (char*)d_ws;
  auto alloc = [&](size_t bytes) { char* r = p; p += (bytes + 255) & ~(size_t)255; return r; };
  float* encWT = (float*)alloc((size_t)CC * HH * 4);
  float* last  = (float*)alloc((size_t)BB * CC * 4);
  float* wst   = (float*)alloc((size_t)BB * 10 * HH * 4);
  float* hf[3];
  for (int i = 0; i < 3; ++i) hf[i] = (float*)alloc((size_t)BB * HH * 4);
  unsigned short* WgH = (unsigned short*)alloc((size_t)4096 * 1120 * 2);
  unsigned short* WgL = (unsigned short*)alloc((size_t)4096 * 1120 * 2);
  unsigned short* XaH = (unsigned short*)alloc((size_t)TT * BB * 96 * 2);
  unsigned short* XaL = (unsigned short*)alloc((size_t)TT * BB * 96 * 2);
  unsigned short* hhi[3]; unsigned short* hlo[3];
  for (int i = 0; i < 3; ++i) {
    hhi[i] = (unsigned short*)alloc((size_t)BB * HH * 2);
    hlo[i] = (unsigned short*)alloc((size_t)BB * HH * 2);
  }
  unsigned short* lpH = (unsigned short*)alloc((size_t)BB * 96 * 2);
  unsigned short* lpL = (unsigned short*)alloc((size_t)BB * 96 * 2);
  if ((size_t)(p - (char*)d_ws) > ws_size) return;  // insufficient workspace

  // ---- one-time prep ----
  prep_wgc<<<dim3((4096u * 1120u) / 256u), 256, 0, stream>>>(gWh, gWi, WgH, WgL);
  prep_xall<<<dim3(((unsigned)TT * BB * 96) / 256u), 256, 0, stream>>>(x, XaH, XaL);
  transpose_encW<<<dim3(CC, HH/256), 256, 0, stream>>>(encW, encWT);
  copy_last_kernel<<<dim3((BB*CC + 255)/256), 256, 0, stream>>>(x, last);
  hipMemsetAsync(hf[0], 0, (size_t)BB * HH * 4, stream);
  hipMemsetAsync(hhi[0], 0, (size_t)BB * HH * 2, stream);
  hipMemsetAsync(hlo[0], 0, (size_t)BB * HH * 2, stream);
  hipMemsetAsync(lpH, 0, (size_t)BB * 96 * 2, stream);
  hipMemsetAsync(lpL, 0, (size_t)BB * 96 * 2, stream);

  const dim3 ggrid(BB / 64, 32);  // 16 x 32 = 512 blocks

  // ---- encoder: 63 GRU steps over x[:, 0..62, :] ----
  int cur = 0;
  for (int t = 0; t < 63; ++t) {
    int nxt = 1 - cur;
    gru_mfma<<<ggrid, 256, 0, stream>>>(
        hhi[cur], hlo[cur], hf[cur],
        XaH + (size_t)t * BB * 96, XaL + (size_t)t * BB * 96,
        WgH, WgL, gbi, gbh, hf[nxt], hhi[nxt], hlo[nxt]);
    cur = nxt;
  }
  // window_history = GRU(h_enc, x[:,63,:]) -> set 2 (persistent)
  gru_mfma<<<ggrid, 256, 0, stream>>>(
      hhi[cur], hlo[cur], hf[cur],
      XaH + (size_t)63 * BB * 96, XaL + (size_t)63 * BB * 96,
      WgH, WgL, gbi, gbh, hf[2], hhi[2], hlo[2]);

  // ---- initial wst ring: rows of buf0 = x[:, 54..63, :] ----
  for (int w = 0; w < 10; ++w)
    wst_row_kernel<<<dim3(HH/256, BB), 256, 0, stream>>>(
        x + (size_t)(54 + w) * CC, XROW, encWT, encb, wst + (size_t)w * HH);

  // ---- decoder: 64 steps ----
  int hc = 2;
  for (int t = 0; t < 64; ++t) {
    if (t > 0) {
      int hn = (t - 1) & 1;
      gru_mfma<<<ggrid, 256, 0, stream>>>(
          hhi[hc], hlo[hc], hf[hc], lpH, lpL,
          WgH, WgL, gbi, gbh, hf[hn], hhi[hn], hlo[hn]);
      hc = hn;
      wst_row_kernel<<<dim3(HH/256, BB), 256, 0, stream>>>(
          last, CC, encWT, encb, wst + (size_t)((t + 9) % 10) * HH);
    }
    mlp_kernel<<<dim3(BB), 256, 0, stream>>>(
        hf[2], hf[hc], wst, t % 10, seqW, seqb, lnA, lnB, outW, outb, mrgW, mrgb,
        last, out + (size_t)t * CC, lpH, lpL);
  }
}